// Round 6
// baseline (312.283 us; speedup 1.0000x reference)
//
#include <hip/hip_runtime.h>
#include <hip/hip_bf16.h>

#define NB 8
#define NN 2048
#define DD 128

typedef __attribute__((ext_vector_type(8))) short short8v;
typedef __attribute__((ext_vector_type(4))) float f32x4;

__device__ __forceinline__ unsigned short f2bf(float x) {
    unsigned int u = __float_as_uint(x);
    u += 0x7FFFu + ((u >> 16) & 1u);
    return (unsigned short)(u >> 16);
}

// ---------- Kernel 1: hp = h@W + b ; s,t row-dots ; hpT = bf16 transpose ----------
__global__ __launch_bounds__(256) void proj_kernel(
    const float* __restrict__ h, const float* __restrict__ W,
    const float* __restrict__ bias, const float* __restrict__ watt,
    float* __restrict__ hp, unsigned short* __restrict__ hpT,
    float* __restrict__ s, float* __restrict__ t)
{
    __shared__ float Ws[64][132];
    __shared__ float hs[64][68];
    const int tid = threadIdx.x;
    const int rowbase = blockIdx.x * 64;
    const int rg = tid >> 3;        // rows 2rg, 2rg+1
    const int dg = tid & 7;         // dims dg*16..+15

    const float4* W4 = (const float4*)W;
    const float4* h4 = (const float4*)h;

    float acc[2][16];
    #pragma unroll
    for (int r = 0; r < 2; ++r)
        #pragma unroll
        for (int d = 0; d < 16; ++d) acc[r][d] = 0.f;

    for (int p = 0; p < 2; ++p) {
        #pragma unroll
        for (int q = 0; q < 8; ++q) {
            int f = tid + 256 * q;
            float4 v = W4[2048 * p + f];
            *(float4*)&Ws[f >> 5][4 * (f & 31)] = v;
        }
        #pragma unroll
        for (int q = 0; q < 4; ++q) {
            int f = tid + 256 * q;
            int r = f >> 4, c4 = f & 15;
            float4 v = h4[(size_t)(rowbase + r) * 32 + 16 * p + c4];
            *(float4*)&hs[r][4 * c4] = v;
        }
        __syncthreads();

        #pragma unroll 8
        for (int k = 0; k < 64; ++k) {
            float h0 = hs[2 * rg][k];
            float h1 = hs[2 * rg + 1][k];
            float4 w0 = *(const float4*)&Ws[k][dg * 16];
            float4 w1 = *(const float4*)&Ws[k][dg * 16 + 4];
            float4 w2 = *(const float4*)&Ws[k][dg * 16 + 8];
            float4 w3 = *(const float4*)&Ws[k][dg * 16 + 12];
            float wv[16] = {w0.x,w0.y,w0.z,w0.w, w1.x,w1.y,w1.z,w1.w,
                            w2.x,w2.y,w2.z,w2.w, w3.x,w3.y,w3.z,w3.w};
            #pragma unroll
            for (int d = 0; d < 16; ++d) {
                acc[0][d] += h0 * wv[d];
                acc[1][d] += h1 * wv[d];
            }
        }
        __syncthreads();
    }

    // bias
    const float4* b4 = (const float4*)bias;
    #pragma unroll
    for (int dq = 0; dq < 4; ++dq) {
        float4 bv = b4[dg * 4 + dq];
        #pragma unroll
        for (int r = 0; r < 2; ++r) {
            acc[r][4 * dq + 0] += bv.x;
            acc[r][4 * dq + 1] += bv.y;
            acc[r][4 * dq + 2] += bv.z;
            acc[r][4 * dq + 3] += bv.w;
        }
    }
    // store hp (f32)
    #pragma unroll
    for (int r = 0; r < 2; ++r) {
        float4* o = (float4*)(hp + (size_t)(rowbase + 2 * rg + r) * 128);
        #pragma unroll
        for (int dq = 0; dq < 4; ++dq) {
            float4 v = {acc[r][4*dq+0], acc[r][4*dq+1], acc[r][4*dq+2], acc[r][4*dq+3]};
            o[dg * 4 + dq] = v;
        }
    }
    // store hpT (bf16, transposed [b][d][j]); u32 packs j-pair (2rg, 2rg+1)
    {
        int rowpair = ((rowbase & (NN - 1)) >> 1) + rg;
        int bb = rowbase >> 11;
        unsigned int* hT32 = (unsigned int*)hpT;
        #pragma unroll
        for (int dd = 0; dd < 16; ++dd) {
            int d = dg * 16 + dd;
            unsigned int pk = (unsigned int)f2bf(acc[0][dd]) |
                              ((unsigned int)f2bf(acc[1][dd]) << 16);
            hT32[(((size_t)bb * 128 + d) << 10) + rowpair] = pk;
        }
    }
    // rowdot: s,t
    const float4* w4 = (const float4*)watt;
    float sp[2] = {0.f, 0.f}, tp[2] = {0.f, 0.f};
    #pragma unroll
    for (int q = 0; q < 4; ++q) {
        float4 wsa = w4[dg * 4 + q];
        float4 wta = w4[32 + dg * 4 + q];
        #pragma unroll
        for (int r = 0; r < 2; ++r) {
            sp[r] += acc[r][4*q+0]*wsa.x + acc[r][4*q+1]*wsa.y
                   + acc[r][4*q+2]*wsa.z + acc[r][4*q+3]*wsa.w;
            tp[r] += acc[r][4*q+0]*wta.x + acc[r][4*q+1]*wta.y
                   + acc[r][4*q+2]*wta.z + acc[r][4*q+3]*wta.w;
        }
    }
    #pragma unroll
    for (int r = 0; r < 2; ++r) {
        float v = sp[r], u = tp[r];
        v += __shfl_xor(v, 1, 64); u += __shfl_xor(u, 1, 64);
        v += __shfl_xor(v, 2, 64); u += __shfl_xor(u, 2, 64);
        v += __shfl_xor(v, 4, 64); u += __shfl_xor(u, 4, 64);
        if (dg == 0) {
            s[rowbase + 2 * rg + r] = v;
            t[rowbase + 2 * rg + r] = u;
        }
    }
}

// ---------- Kernel 2: barrier-free fused GAT attention ----------
// 1024 blocks (B x N/16), 256 thr (4 waves). 16 rows/block.
// Wave wv owns j in [wv*512, wv*512+512): 16 K-tiles of 32.
// Lane (r=lane&15, kg=lane>>4): computes its OWN A-fragment in registers
// (p for row r, j = kg*8..+7), loads B-fragments per-lane from hpT.
// 8 persistent acc (all 128 dims). ZERO main-loop barriers; one final
// LDS combine across waves.
__global__ __launch_bounds__(256, 4) void fused_kernel(
    const float* __restrict__ a, const float* __restrict__ hp,
    const unsigned short* __restrict__ hpT,
    const float* __restrict__ s, const float* __restrict__ t,
    const float* __restrict__ battp, float* __restrict__ out)
{
    __shared__ float red[4][16][128];     // 32 KB, epilogue only
    __shared__ float wsum_lds[4][16];

    const int tid  = threadIdx.x;
    const int lane = tid & 63;
    const int wv   = tid >> 6;
    const int b     = blockIdx.x >> 7;
    const int ibase = (blockIdx.x & 127) * 16;
    const int bN    = b * NN;

    const int c  = lane & 15;     // A row / B col / C col index
    const int kg = lane >> 4;     // k-slice: k = kg*8..+7

    const float s_reg = s[bN + ibase + c] + battp[0];
    const float* arow = a + (size_t)(bN + ibase + c) * NN;
    const float* tb   = t + bN;
    const unsigned short* pB = hpT + ((size_t)(b * 128 + c) << 11);
    const int jw = wv * 512 + (kg << 3);   // this lane's j base

    float wsum_p = 0.f;
    f32x4 acc[8];
    #pragma unroll
    for (int n = 0; n < 8; ++n) acc[n] = (f32x4){0.f, 0.f, 0.f, 0.f};

    float4 av0a, av0b, tv0a, tv0b;   // prefetch set 0 (even tiles)
    float4 av1a, av1b, tv1a, tv1b;   // prefetch set 1 (odd tiles)

#define LOADAT(AVA, AVB, TVA, TVB, tt) do { \
        int j = jw + (tt) * 32; \
        AVA = *(const float4*)(arow + j); \
        AVB = *(const float4*)(arow + j + 4); \
        TVA = *(const float4*)(tb + j); \
        TVB = *(const float4*)(tb + j + 4); \
    } while (0)

#define BODY(tt, AVA, AVB, TVA, TVB) do { \
        int j = jw + (tt) * 32; \
        const unsigned short* pBt = pB + j; \
        short8v B0 = *(const short8v*)(pBt); \
        short8v B1 = *(const short8v*)(pBt + (1 << 15)); \
        short8v B2 = *(const short8v*)(pBt + (2 << 15)); \
        short8v B3 = *(const short8v*)(pBt + (3 << 15)); \
        short8v B4 = *(const short8v*)(pBt + (4 << 15)); \
        short8v B5 = *(const short8v*)(pBt + (5 << 15)); \
        short8v B6 = *(const short8v*)(pBt + (6 << 15)); \
        short8v B7 = *(const short8v*)(pBt + (7 << 15)); \
        float p0 = __expf(fmaxf(s_reg + TVA.x, 0.f)) * AVA.x; \
        float p1 = __expf(fmaxf(s_reg + TVA.y, 0.f)) * AVA.y; \
        float p2 = __expf(fmaxf(s_reg + TVA.z, 0.f)) * AVA.z; \
        float p3 = __expf(fmaxf(s_reg + TVA.w, 0.f)) * AVA.w; \
        float p4 = __expf(fmaxf(s_reg + TVB.x, 0.f)) * AVB.x; \
        float p5 = __expf(fmaxf(s_reg + TVB.y, 0.f)) * AVB.y; \
        float p6 = __expf(fmaxf(s_reg + TVB.z, 0.f)) * AVB.z; \
        float p7 = __expf(fmaxf(s_reg + TVB.w, 0.f)) * AVB.w; \
        wsum_p += ((p0 + p1) + (p2 + p3)) + ((p4 + p5) + (p6 + p7)); \
        union { uint4 u; short8v sv; } Au; \
        Au.u.x = (unsigned int)f2bf(p0) | ((unsigned int)f2bf(p1) << 16); \
        Au.u.y = (unsigned int)f2bf(p2) | ((unsigned int)f2bf(p3) << 16); \
        Au.u.z = (unsigned int)f2bf(p4) | ((unsigned int)f2bf(p5) << 16); \
        Au.u.w = (unsigned int)f2bf(p6) | ((unsigned int)f2bf(p7) << 16); \
        if ((tt) + 2 < 16) LOADAT(AVA, AVB, TVA, TVB, (tt) + 2); \
        acc[0] = __builtin_amdgcn_mfma_f32_16x16x32_bf16(Au.sv, B0, acc[0], 0, 0, 0); \
        acc[1] = __builtin_amdgcn_mfma_f32_16x16x32_bf16(Au.sv, B1, acc[1], 0, 0, 0); \
        acc[2] = __builtin_amdgcn_mfma_f32_16x16x32_bf16(Au.sv, B2, acc[2], 0, 0, 0); \
        acc[3] = __builtin_amdgcn_mfma_f32_16x16x32_bf16(Au.sv, B3, acc[3], 0, 0, 0); \
        acc[4] = __builtin_amdgcn_mfma_f32_16x16x32_bf16(Au.sv, B4, acc[4], 0, 0, 0); \
        acc[5] = __builtin_amdgcn_mfma_f32_16x16x32_bf16(Au.sv, B5, acc[5], 0, 0, 0); \
        acc[6] = __builtin_amdgcn_mfma_f32_16x16x32_bf16(Au.sv, B6, acc[6], 0, 0, 0); \
        acc[7] = __builtin_amdgcn_mfma_f32_16x16x32_bf16(Au.sv, B7, acc[7], 0, 0, 0); \
    } while (0)

    LOADAT(av0a, av0b, tv0a, tv0b, 0);
    LOADAT(av1a, av1b, tv1a, tv1b, 1);

    for (int tt2 = 0; tt2 < 16; tt2 += 2) {
        BODY(tt2,     av0a, av0b, tv0a, tv0b);
        BODY(tt2 + 1, av1a, av1b, tv1a, tv1b);
    }
#undef LOADAT
#undef BODY

    // ---- epilogue (single barrier) ----
    {
        float v = wsum_p;
        v += __shfl_xor(v, 16, 64);
        v += __shfl_xor(v, 32, 64);
        if (kg == 0) wsum_lds[wv][c] = v;
    }
    #pragma unroll
    for (int n = 0; n < 8; ++n) {
        #pragma unroll
        for (int qq = 0; qq < 4; ++qq)
            red[wv][kg * 4 + qq][n * 16 + c] = acc[n][qq];
    }
    __syncthreads();

    {
        const int row = tid >> 4;
        const int col = (tid & 15) * 8;
        float inv = 1.0f / (wsum_lds[0][row] + wsum_lds[1][row] +
                            wsum_lds[2][row] + wsum_lds[3][row]);
        float s0x = 0.f, s0y = 0.f, s0z = 0.f, s0w = 0.f;
        float s1x = 0.f, s1y = 0.f, s1z = 0.f, s1w = 0.f;
        #pragma unroll
        for (int u = 0; u < 4; ++u) {
            float4 x0 = *(const float4*)&red[u][row][col];
            float4 x1 = *(const float4*)&red[u][row][col + 4];
            s0x += x0.x; s0y += x0.y; s0z += x0.z; s0w += x0.w;
            s1x += x1.x; s1y += x1.y; s1z += x1.z; s1w += x1.w;
        }
        size_t gr = (size_t)(bN + ibase + row);
        const float* hpb = hp + gr * 128 + col;
        float4 h0 = *(const float4*)(hpb);
        float4 h1 = *(const float4*)(hpb + 4);
        float4 o0 = {s0x * inv + h0.x, s0y * inv + h0.y,
                     s0z * inv + h0.z, s0w * inv + h0.w};
        float4 o1 = {s1x * inv + h1.x, s1y * inv + h1.y,
                     s1z * inv + h1.z, s1w * inv + h1.w};
        float* ob = out + gr * 128 + col;
        *(float4*)(ob)     = o0;
        *(float4*)(ob + 4) = o1;
    }
}

extern "C" void kernel_launch(void* const* d_in, const int* in_sizes, int n_in,
                              void* d_out, int out_size, void* d_ws, size_t ws_size,
                              hipStream_t stream) {
    const float* a      = (const float*)d_in[0];   // [B,N,N]
    const float* h      = (const float*)d_in[1];   // [B,N,128]
    const float* W_proj = (const float*)d_in[2];   // [128,128]
    const float* b_proj = (const float*)d_in[3];   // [128]
    const float* w_att  = (const float*)d_in[4];   // [256]
    const float* b_att  = (const float*)d_in[5];   // [1]
    float* out = (float*)d_out;

    float* hp = (float*)d_ws;                              // [B*N,128] f32
    float* s  = hp + (size_t)NB * NN * DD;                 // [B*N]
    float* t  = s + (size_t)NB * NN;                       // [B*N]
    unsigned short* hpT = (unsigned short*)(t + (size_t)NB * NN); // [B][128][N] bf16

    proj_kernel<<<256, 256, 0, stream>>>(h, W_proj, b_proj, w_att, hp, hpT, s, t);
    fused_kernel<<<1024, 256, 0, stream>>>(a, hp, hpT, s, t, b_att, out);
}

// Round 7
// 310.225 us; speedup vs baseline: 1.0066x; 1.0066x over previous
//
#include <hip/hip_runtime.h>
#include <hip/hip_bf16.h>

#define NB 8
#define NN 2048
#define DD 128

typedef __attribute__((ext_vector_type(8))) short short8v;
typedef __attribute__((ext_vector_type(4))) float f32x4;

__device__ __forceinline__ unsigned short f2bf(float x) {
    unsigned int u = __float_as_uint(x);
    u += 0x7FFFu + ((u >> 16) & 1u);
    return (unsigned short)(u >> 16);
}

// ---------- Kernel 1: hp = h@W + b ; s,t row-dots ; hpT = bf16 transpose ----------
__global__ __launch_bounds__(256) void proj_kernel(
    const float* __restrict__ h, const float* __restrict__ W,
    const float* __restrict__ bias, const float* __restrict__ watt,
    float* __restrict__ hp, unsigned short* __restrict__ hpT,
    float* __restrict__ s, float* __restrict__ t)
{
    __shared__ float Ws[64][132];
    __shared__ float hs[64][68];
    const int tid = threadIdx.x;
    const int rowbase = blockIdx.x * 64;
    const int rg = tid >> 3;        // rows 2rg, 2rg+1
    const int dg = tid & 7;         // dims dg*16..+15

    const float4* W4 = (const float4*)W;
    const float4* h4 = (const float4*)h;

    float acc[2][16];
    #pragma unroll
    for (int r = 0; r < 2; ++r)
        #pragma unroll
        for (int d = 0; d < 16; ++d) acc[r][d] = 0.f;

    for (int p = 0; p < 2; ++p) {
        #pragma unroll
        for (int q = 0; q < 8; ++q) {
            int f = tid + 256 * q;
            float4 v = W4[2048 * p + f];
            *(float4*)&Ws[f >> 5][4 * (f & 31)] = v;
        }
        #pragma unroll
        for (int q = 0; q < 4; ++q) {
            int f = tid + 256 * q;
            int r = f >> 4, c4 = f & 15;
            float4 v = h4[(size_t)(rowbase + r) * 32 + 16 * p + c4];
            *(float4*)&hs[r][4 * c4] = v;
        }
        __syncthreads();

        #pragma unroll 8
        for (int k = 0; k < 64; ++k) {
            float h0 = hs[2 * rg][k];
            float h1 = hs[2 * rg + 1][k];
            float4 w0 = *(const float4*)&Ws[k][dg * 16];
            float4 w1 = *(const float4*)&Ws[k][dg * 16 + 4];
            float4 w2 = *(const float4*)&Ws[k][dg * 16 + 8];
            float4 w3 = *(const float4*)&Ws[k][dg * 16 + 12];
            float wv[16] = {w0.x,w0.y,w0.z,w0.w, w1.x,w1.y,w1.z,w1.w,
                            w2.x,w2.y,w2.z,w2.w, w3.x,w3.y,w3.z,w3.w};
            #pragma unroll
            for (int d = 0; d < 16; ++d) {
                acc[0][d] += h0 * wv[d];
                acc[1][d] += h1 * wv[d];
            }
        }
        __syncthreads();
    }

    // bias
    const float4* b4 = (const float4*)bias;
    #pragma unroll
    for (int dq = 0; dq < 4; ++dq) {
        float4 bv = b4[dg * 4 + dq];
        #pragma unroll
        for (int r = 0; r < 2; ++r) {
            acc[r][4 * dq + 0] += bv.x;
            acc[r][4 * dq + 1] += bv.y;
            acc[r][4 * dq + 2] += bv.z;
            acc[r][4 * dq + 3] += bv.w;
        }
    }
    // store hp (f32)
    #pragma unroll
    for (int r = 0; r < 2; ++r) {
        float4* o = (float4*)(hp + (size_t)(rowbase + 2 * rg + r) * 128);
        #pragma unroll
        for (int dq = 0; dq < 4; ++dq) {
            float4 v = {acc[r][4*dq+0], acc[r][4*dq+1], acc[r][4*dq+2], acc[r][4*dq+3]};
            o[dg * 4 + dq] = v;
        }
    }
    // store hpT (bf16, transposed [b][d][j]); u32 packs j-pair (2rg, 2rg+1)
    {
        int rowpair = ((rowbase & (NN - 1)) >> 1) + rg;
        int bb = rowbase >> 11;
        unsigned int* hT32 = (unsigned int*)hpT;
        #pragma unroll
        for (int dd = 0; dd < 16; ++dd) {
            int d = dg * 16 + dd;
            unsigned int pk = (unsigned int)f2bf(acc[0][dd]) |
                              ((unsigned int)f2bf(acc[1][dd]) << 16);
            hT32[(((size_t)bb * 128 + d) << 10) + rowpair] = pk;
        }
    }
    // rowdot: s,t
    const float4* w4 = (const float4*)watt;
    float sp[2] = {0.f, 0.f}, tp[2] = {0.f, 0.f};
    #pragma unroll
    for (int q = 0; q < 4; ++q) {
        float4 wsa = w4[dg * 4 + q];
        float4 wta = w4[32 + dg * 4 + q];
        #pragma unroll
        for (int r = 0; r < 2; ++r) {
            sp[r] += acc[r][4*q+0]*wsa.x + acc[r][4*q+1]*wsa.y
                   + acc[r][4*q+2]*wsa.z + acc[r][4*q+3]*wsa.w;
            tp[r] += acc[r][4*q+0]*wta.x + acc[r][4*q+1]*wta.y
                   + acc[r][4*q+2]*wta.z + acc[r][4*q+3]*wta.w;
        }
    }
    #pragma unroll
    for (int r = 0; r < 2; ++r) {
        float v = sp[r], u = tp[r];
        v += __shfl_xor(v, 1, 64); u += __shfl_xor(u, 1, 64);
        v += __shfl_xor(v, 2, 64); u += __shfl_xor(u, 2, 64);
        v += __shfl_xor(v, 4, 64); u += __shfl_xor(u, 4, 64);
        if (dg == 0) {
            s[rowbase + 2 * rg + r] = v;
            t[rowbase + 2 * rg + r] = u;
        }
    }
}

// ---------- Kernel 2: barrier-free fused GAT attention ----------
// 1024 blocks (B x N/16), 256 thr (4 waves). 16 rows/block.
// Wave wv owns j in [wv*512, wv*512+512): 16 K-tiles of 32.
// Lane (c=lane&15, kg=lane>>4): builds its OWN A-fragment in registers
// (p for row c, j = kg*8..+7) via bit_cast (NO union -> no scratch),
// loads B-fragments per-lane from hpT. 8 persistent acc (all 128 dims).
// ZERO main-loop barriers; one final LDS combine across waves.
__global__ __launch_bounds__(256, 4) void fused_kernel(
    const float* __restrict__ a, const float* __restrict__ hp,
    const unsigned short* __restrict__ hpT,
    const float* __restrict__ s, const float* __restrict__ t,
    const float* __restrict__ battp, float* __restrict__ out)
{
    __shared__ float red[4][16][128];     // 32 KB, epilogue only
    __shared__ float wsum_lds[4][16];

    const int tid  = threadIdx.x;
    const int lane = tid & 63;
    const int wv   = tid >> 6;
    const int b     = blockIdx.x >> 7;
    const int ibase = (blockIdx.x & 127) * 16;
    const int bN    = b * NN;

    const int c  = lane & 15;     // A row / B col / C col index
    const int kg = lane >> 4;     // k-slice: k = kg*8..+7

    const float s_reg = s[bN + ibase + c] + battp[0];
    const float* arow = a + (size_t)(bN + ibase + c) * NN;
    const float* tb   = t + bN;
    const unsigned short* pB = hpT + ((size_t)(b * 128 + c) << 11);
    const int jw = wv * 512 + (kg << 3);   // this lane's j base

    float wsum_p = 0.f;
    f32x4 acc[8];
    #pragma unroll
    for (int n = 0; n < 8; ++n) acc[n] = (f32x4){0.f, 0.f, 0.f, 0.f};

    float4 av0a, av0b, tv0a, tv0b;   // prefetch set 0 (even tiles)
    float4 av1a, av1b, tv1a, tv1b;   // prefetch set 1 (odd tiles)

#define LOADAT(AVA, AVB, TVA, TVB, tt) do { \
        int j = jw + (tt) * 32; \
        AVA = *(const float4*)(arow + j); \
        AVB = *(const float4*)(arow + j + 4); \
        TVA = *(const float4*)(tb + j); \
        TVB = *(const float4*)(tb + j + 4); \
    } while (0)

#define BODY(tt, AVA, AVB, TVA, TVB) do { \
        int j = jw + (tt) * 32; \
        const unsigned short* pBt = pB + j; \
        short8v B0 = *(const short8v*)(pBt); \
        short8v B1 = *(const short8v*)(pBt + (1 << 15)); \
        short8v B2 = *(const short8v*)(pBt + (2 << 15)); \
        short8v B3 = *(const short8v*)(pBt + (3 << 15)); \
        short8v B4 = *(const short8v*)(pBt + (4 << 15)); \
        short8v B5 = *(const short8v*)(pBt + (5 << 15)); \
        short8v B6 = *(const short8v*)(pBt + (6 << 15)); \
        short8v B7 = *(const short8v*)(pBt + (7 << 15)); \
        float p0 = __expf(fmaxf(s_reg + TVA.x, 0.f)) * AVA.x; \
        float p1 = __expf(fmaxf(s_reg + TVA.y, 0.f)) * AVA.y; \
        float p2 = __expf(fmaxf(s_reg + TVA.z, 0.f)) * AVA.z; \
        float p3 = __expf(fmaxf(s_reg + TVA.w, 0.f)) * AVA.w; \
        float p4 = __expf(fmaxf(s_reg + TVB.x, 0.f)) * AVB.x; \
        float p5 = __expf(fmaxf(s_reg + TVB.y, 0.f)) * AVB.y; \
        float p6 = __expf(fmaxf(s_reg + TVB.z, 0.f)) * AVB.z; \
        float p7 = __expf(fmaxf(s_reg + TVB.w, 0.f)) * AVB.w; \
        wsum_p += ((p0 + p1) + (p2 + p3)) + ((p4 + p5) + (p6 + p7)); \
        uint4 Au; \
        Au.x = (unsigned int)f2bf(p0) | ((unsigned int)f2bf(p1) << 16); \
        Au.y = (unsigned int)f2bf(p2) | ((unsigned int)f2bf(p3) << 16); \
        Au.z = (unsigned int)f2bf(p4) | ((unsigned int)f2bf(p5) << 16); \
        Au.w = (unsigned int)f2bf(p6) | ((unsigned int)f2bf(p7) << 16); \
        short8v Asv = __builtin_bit_cast(short8v, Au); \
        if ((tt) + 2 < 16) LOADAT(AVA, AVB, TVA, TVB, (tt) + 2); \
        acc[0] = __builtin_amdgcn_mfma_f32_16x16x32_bf16(Asv, B0, acc[0], 0, 0, 0); \
        acc[1] = __builtin_amdgcn_mfma_f32_16x16x32_bf16(Asv, B1, acc[1], 0, 0, 0); \
        acc[2] = __builtin_amdgcn_mfma_f32_16x16x32_bf16(Asv, B2, acc[2], 0, 0, 0); \
        acc[3] = __builtin_amdgcn_mfma_f32_16x16x32_bf16(Asv, B3, acc[3], 0, 0, 0); \
        acc[4] = __builtin_amdgcn_mfma_f32_16x16x32_bf16(Asv, B4, acc[4], 0, 0, 0); \
        acc[5] = __builtin_amdgcn_mfma_f32_16x16x32_bf16(Asv, B5, acc[5], 0, 0, 0); \
        acc[6] = __builtin_amdgcn_mfma_f32_16x16x32_bf16(Asv, B6, acc[6], 0, 0, 0); \
        acc[7] = __builtin_amdgcn_mfma_f32_16x16x32_bf16(Asv, B7, acc[7], 0, 0, 0); \
    } while (0)

    LOADAT(av0a, av0b, tv0a, tv0b, 0);
    LOADAT(av1a, av1b, tv1a, tv1b, 1);

    for (int tt2 = 0; tt2 < 16; tt2 += 2) {
        BODY(tt2,     av0a, av0b, tv0a, tv0b);
        BODY(tt2 + 1, av1a, av1b, tv1a, tv1b);
    }
#undef LOADAT
#undef BODY

    // ---- epilogue (single barrier) ----
    {
        float v = wsum_p;
        v += __shfl_xor(v, 16, 64);
        v += __shfl_xor(v, 32, 64);
        if (kg == 0) wsum_lds[wv][c] = v;
    }
    #pragma unroll
    for (int n = 0; n < 8; ++n) {
        #pragma unroll
        for (int qq = 0; qq < 4; ++qq)
            red[wv][kg * 4 + qq][n * 16 + c] = acc[n][qq];
    }
    __syncthreads();

    {
        const int row = tid >> 4;
        const int col = (tid & 15) * 8;
        float inv = 1.0f / (wsum_lds[0][row] + wsum_lds[1][row] +
                            wsum_lds[2][row] + wsum_lds[3][row]);
        float s0x = 0.f, s0y = 0.f, s0z = 0.f, s0w = 0.f;
        float s1x = 0.f, s1y = 0.f, s1z = 0.f, s1w = 0.f;
        #pragma unroll
        for (int u = 0; u < 4; ++u) {
            float4 x0 = *(const float4*)&red[u][row][col];
            float4 x1 = *(const float4*)&red[u][row][col + 4];
            s0x += x0.x; s0y += x0.y; s0z += x0.z; s0w += x0.w;
            s1x += x1.x; s1y += x1.y; s1z += x1.z; s1w += x1.w;
        }
        size_t gr = (size_t)(bN + ibase + row);
        const float* hpb = hp + gr * 128 + col;
        float4 h0 = *(const float4*)(hpb);
        float4 h1 = *(const float4*)(hpb + 4);
        float4 o0 = {s0x * inv + h0.x, s0y * inv + h0.y,
                     s0z * inv + h0.z, s0w * inv + h0.w};
        float4 o1 = {s1x * inv + h1.x, s1y * inv + h1.y,
                     s1z * inv + h1.z, s1w * inv + h1.w};
        float* ob = out + gr * 128 + col;
        *(float4*)(ob)     = o0;
        *(float4*)(ob + 4) = o1;
    }
}

extern "C" void kernel_launch(void* const* d_in, const int* in_sizes, int n_in,
                              void* d_out, int out_size, void* d_ws, size_t ws_size,
                              hipStream_t stream) {
    const float* a      = (const float*)d_in[0];   // [B,N,N]
    const float* h      = (const float*)d_in[1];   // [B,N,128]
    const float* W_proj = (const float*)d_in[2];   // [128,128]
    const float* b_proj = (const float*)d_in[3];   // [128]
    const float* w_att  = (const float*)d_in[4];   // [256]
    const float* b_att  = (const float*)d_in[5];   // [1]
    float* out = (float*)d_out;

    float* hp = (float*)d_ws;                              // [B*N,128] f32
    float* s  = hp + (size_t)NB * NN * DD;                 // [B*N]
    float* t  = s + (size_t)NB * NN;                       // [B*N]
    unsigned short* hpT = (unsigned short*)(t + (size_t)NB * NN); // [B][128][N] bf16

    proj_kernel<<<256, 256, 0, stream>>>(h, W_proj, b_proj, w_att, hp, hpT, s, t);
    fused_kernel<<<1024, 256, 0, stream>>>(a, hp, hpT, s, t, b_att, out);
}